// Round 1
// baseline (154.000 us; speedup 1.0000x reference)
//
#include <hip/hip_runtime.h>
#include <hip/hip_bf16.h>
#include <stdint.h>

#define NHEADS 12
#define HSZ 64
#define BATCH 8
#define SEQ 1024
#define DIN 1024
#define NPROJ 1536   // NHEADS*HSZ*2
#define MTOK 8192    // BATCH*SEQ
#define NEGV 1e12f

typedef float  f32x4  __attribute__((ext_vector_type(4)));
typedef __bf16 bf16x8 __attribute__((ext_vector_type(8)));

__device__ __forceinline__ ushort f2bf(float x) {
  union { float f; uint32_t u; } v; v.f = x;
  uint32_t r = v.u + 0x7FFFu + ((v.u >> 16) & 1u);
  return (ushort)(r >> 16);
}

__device__ __forceinline__ void async16(const void* g, void* l) {
  __builtin_amdgcn_global_load_lds(
      (const __attribute__((address_space(1))) uint32_t*)g,
      (__attribute__((address_space(3))) uint32_t*)l,
      16, 0, 0);
}

// ---------------- prep kernels ----------------

__global__ void k_cvt(const float4* __restrict__ in, ushort4* __restrict__ out, int n4) {
  int i = blockIdx.x * blockDim.x + threadIdx.x;
  const int stride = gridDim.x * blockDim.x;
  for (; i < n4; i += stride) {
    float4 v = in[i];
    ushort4 o;
    o.x = f2bf(v.x); o.y = f2bf(v.y); o.z = f2bf(v.z); o.w = f2bf(v.w);
    out[i] = o;
  }
}

// Wt[n][k] = bf16(W[k][n]);  W: [DIN][NPROJ] f32, Wt: [NPROJ][DIN] bf16
__global__ __launch_bounds__(256) void k_transpose(const float* __restrict__ W,
                                                   ushort* __restrict__ Wt) {
  __shared__ float tile[64][65];
  const int n0 = blockIdx.x * 64;
  const int k0 = blockIdx.y * 64;
  const int c  = threadIdx.x & 63;
  const int r0 = (threadIdx.x >> 6) * 16;
  #pragma unroll
  for (int rr = 0; rr < 16; ++rr)
    tile[r0 + rr][c] = W[(size_t)(k0 + r0 + rr) * NPROJ + n0 + c];
  __syncthreads();
  #pragma unroll
  for (int rr = 0; rr < 16; ++rr)
    Wt[(size_t)(n0 + r0 + rr) * DIN + k0 + c] = f2bf(tile[c][r0 + rr]);
}

// tab[s][i] = {sin, cos} of s / 10000^(2i/64);  [SEQ][32][2] f32
__global__ void k_rope(float* __restrict__ tab) {
  const int t = blockIdx.x * 256 + threadIdx.x;  // 32768 total
  const int s = t >> 5, i = t & 31;
  const float p   = powf(10000.0f, (float)i / 32.0f);
  const float ang = (float)s / p;
  tab[2 * t]     = sinf(ang);
  tab[2 * t + 1] = cosf(ang);
}

// ---------------- projection GEMM + RoPE ----------------
// A: [MTOK][DIN] bf16, Bt: [NPROJ][DIN] bf16 (pre-transposed W)
// out: Qb/Kb [BATCH*NHEADS][SEQ][64] bf16 (RoPE'd)
__global__ __launch_bounds__(256) void k_gemm_proj(
    const ushort* __restrict__ A, const ushort* __restrict__ Bt,
    const float* __restrict__ bias, const float* __restrict__ tab,
    ushort* __restrict__ Qb, ushort* __restrict__ Kb) {
  __shared__ __align__(16) ushort As[128 * 32];
  __shared__ __align__(16) ushort Bs[128 * 32];
  const int tid  = threadIdx.x;
  const int lane = tid & 63;
  const int wid  = tid >> 6;
  const int wm = wid >> 1, wn = wid & 1;
  const int m0 = blockIdx.x * 128;
  const int n0 = blockIdx.y * 128;

  // staging: linear LDS layout [row][32] bf16 (64 B rows, 4 x 16B slots).
  // swizzle: slot_lds = slot_global ^ ((row>>1)&3)  (involution; applied to SOURCE)
  const int off0 = tid * 16;         // issue-0 linear byte offset in tile
  const int off1 = 4096 + tid * 16;  // issue-1
  const int r0 = off0 >> 6, s0 = (off0 >> 4) & 3;
  const int r1 = off1 >> 6, s1 = (off1 >> 4) & 3;
  const int g0 = (s0 ^ ((r0 >> 1) & 3)) * 8;  // global k-chunk (elements)
  const int g1 = (s1 ^ ((r1 >> 1) & 3)) * 8;
  const ushort* gA0 = A  + (size_t)(m0 + r0) * DIN + g0;
  const ushort* gA1 = A  + (size_t)(m0 + r1) * DIN + g1;
  const ushort* gB0 = Bt + (size_t)(n0 + r0) * DIN + g0;
  const ushort* gB1 = Bt + (size_t)(n0 + r1) * DIN + g1;
  ushort* lA0 = As + wid * 512;         // byte base wid*1024 (+lane*16 by HW)
  ushort* lA1 = As + 2048 + wid * 512;
  ushort* lB0 = Bs + wid * 512;
  ushort* lB1 = Bs + 2048 + wid * 512;

  // fragment read offsets (ushort units), same swizzle on READ side
  const int kb = lane >> 4;
  int aoff[4], boff[4];
  #pragma unroll
  for (int i = 0; i < 4; ++i) {
    const int ra = wm * 64 + i * 16 + (lane & 15);
    aoff[i] = ra * 32 + (kb ^ ((ra >> 1) & 3)) * 8;
    const int rb = wn * 64 + i * 16 + (lane & 15);
    boff[i] = rb * 32 + (kb ^ ((rb >> 1) & 3)) * 8;
  }

  f32x4 acc[4][4] = {};
  for (int kt = 0; kt < DIN / 32; ++kt) {
    __syncthreads();
    const int ko = kt * 32;
    async16(gA0 + ko, lA0);
    async16(gA1 + ko, lA1);
    async16(gB0 + ko, lB0);
    async16(gB1 + ko, lB1);
    __syncthreads();
    bf16x8 af[4], bfr[4];
    #pragma unroll
    for (int i = 0; i < 4; ++i) {
      af[i]  = *(const bf16x8*)(As + aoff[i]);
      bfr[i] = *(const bf16x8*)(Bs + boff[i]);
    }
    #pragma unroll
    for (int mi = 0; mi < 4; ++mi)
      #pragma unroll
      for (int ni = 0; ni < 4; ++ni)
        acc[mi][ni] = __builtin_amdgcn_mfma_f32_16x16x32_bf16(af[mi], bfr[ni], acc[mi][ni], 0, 0, 0);
  }

  // epilogue: bias + RoPE + scatter to Q/K (bf16)
  const int b = m0 >> 10;  // 128-tile never crosses a batch boundary
  const int baserow = m0 + wm * 64 + ((lane >> 4) << 2);
  #pragma unroll
  for (int ni = 0; ni < 4; ++ni) {
    const int n = n0 + wn * 64 + ni * 16 + (lane & 15);
    const float bv = bias[n];
    const int h  = n >> 7;
    const int c  = n & 127;
    const int d  = c & 63;
    const int pi = d >> 1;
    ushort* dst = ((c < 64) ? Qb : Kb) + (size_t)(b * NHEADS + h) * SEQ * 64 + d;
    #pragma unroll
    for (int mi = 0; mi < 4; ++mi) {
      #pragma unroll
      for (int j = 0; j < 4; ++j) {
        const int gm = baserow + mi * 16 + j;
        const int s  = gm & (SEQ - 1);
        float v = acc[mi][ni][j] + bv;
        float p = __shfl_xor(v, 1);  // paired channel (n^1) lives in lane^1
        float2 sc = ((const float2*)tab)[s * 32 + pi];
        float o = (d & 1) ? fmaf(v, sc.y, p * sc.x) : fmaf(v, sc.y, -p * sc.x);
        dst[(size_t)s * 64] = f2bf(o);
      }
    }
  }
}

// ---------------- logits: batched QK^T + mask ----------------
__global__ __launch_bounds__(256) void k_logits(
    const ushort* __restrict__ Qb, const ushort* __restrict__ Kb,
    const int* __restrict__ mask, float* __restrict__ out) {
  __shared__ __align__(16) ushort Qs[128 * 64];
  __shared__ __align__(16) ushort Ks[128 * 64];
  const int tid  = threadIdx.x;
  const int lane = tid & 63;
  const int wid  = tid >> 6;
  const int wm = wid >> 1, wn = wid & 1;
  const int bh = blockIdx.z;
  const int b  = bh / NHEADS;
  const int m0 = blockIdx.x * 128, n0 = blockIdx.y * 128;
  const ushort* Qt = Qb + (size_t)bh * SEQ * 64;
  const ushort* Kt = Kb + (size_t)bh * SEQ * 64;

  // stage 128x64 bf16 tiles; rows are 128 B = 8 x 16B slots.
  // swizzle slot' = slot ^ (row&7) (else 32-way bank conflict on ds_read_b128)
  #pragma unroll
  for (int is = 0; is < 4; ++is) {
    const int off = is * 4096 + tid * 16;
    const int row = off >> 7;
    const int g8  = ((((off >> 4) & 7) ^ (row & 7))) * 8;
    async16(Qt + (size_t)(m0 + row) * 64 + g8, Qs + is * 2048 + wid * 512);
    async16(Kt + (size_t)(n0 + row) * 64 + g8, Ks + is * 2048 + wid * 512);
  }
  __syncthreads();

  f32x4 acc[4][4] = {};
  const int kb = lane >> 4;
  #pragma unroll
  for (int ks = 0; ks < 2; ++ks) {
    bf16x8 qf[4], kf[4];
    #pragma unroll
    for (int i = 0; i < 4; ++i) {
      const int rq = wm * 64 + i * 16 + (lane & 15);
      qf[i] = *(const bf16x8*)(Qs + rq * 64 + ((ks * 4 + kb) ^ (rq & 7)) * 8);
      const int rk = wn * 64 + i * 16 + (lane & 15);
      kf[i] = *(const bf16x8*)(Ks + rk * 64 + ((ks * 4 + kb) ^ (rk & 7)) * 8);
    }
    #pragma unroll
    for (int mi = 0; mi < 4; ++mi)
      #pragma unroll
      for (int ni = 0; ni < 4; ++ni)
        acc[mi][ni] = __builtin_amdgcn_mfma_f32_16x16x32_bf16(qf[mi], kf[ni], acc[mi][ni], 0, 0, 0);
  }

  const int* mb = mask + b * SEQ;
  float* ob = out + (size_t)bh * SEQ * SEQ;
  const int mrow0 = m0 + wm * 64 + ((lane >> 4) << 2);
  const int ncol0 = n0 + wn * 64 + (lane & 15);
  float npen[4];
  int gn_[4];
  #pragma unroll
  for (int ni = 0; ni < 4; ++ni) {
    gn_[ni]  = ncol0 + ni * 16;
    npen[ni] = mb[gn_[ni]] ? 0.0f : NEGV;
  }
  #pragma unroll
  for (int mi = 0; mi < 4; ++mi) {
    #pragma unroll
    for (int j = 0; j < 4; ++j) {
      const int gm = mrow0 + mi * 16 + j;
      const float mpen = mb[gm] ? 0.0f : NEGV;
      float* orow = ob + (size_t)gm * SEQ;
      #pragma unroll
      for (int ni = 0; ni < 4; ++ni) {
        const int gn = gn_[ni];
        const float tpen = (gm > gn) ? NEGV : 0.0f;
        orow[gn] = (acc[mi][ni][j] - (mpen + npen[ni] + tpen)) * 0.125f;
      }
    }
  }
}

// ---------------- launcher ----------------
extern "C" void kernel_launch(void* const* d_in, const int* in_sizes, int n_in,
                              void* d_out, int out_size, void* d_ws, size_t ws_size,
                              hipStream_t stream) {
  const float* inp  = (const float*)d_in[0];  // [8][1024][1024]
  const float* W    = (const float*)d_in[1];  // [1024][1536]
  const float* bias = (const float*)d_in[2];  // [1536]
  const int*   mask = (const int*)d_in[3];    // [8][1024]
  float* out = (float*)d_out;                 // [8][12][1024][1024]

  char* ws = (char*)d_ws;
  ushort* A16  = (ushort*)ws;                 // 16,777,216 B
  ushort* WT16 = (ushort*)(ws + 16777216);    //  3,145,728 B
  float*  tab  = (float*)(ws + 19922944);     //    262,144 B
  ushort* Qb   = (ushort*)(ws + 20185088);    // 12,582,912 B
  ushort* Kb   = (ushort*)(ws + 32768000);    // 12,582,912 B  (total ~45.4 MB)

  k_cvt<<<2048, 256, 0, stream>>>((const float4*)inp, (ushort4*)A16, MTOK * DIN / 4);
  k_transpose<<<dim3(NPROJ / 64, DIN / 64), 256, 0, stream>>>(W, WT16);
  k_rope<<<(SEQ * 32) / 256, 256, 0, stream>>>(tab);
  k_gemm_proj<<<dim3(MTOK / 128, NPROJ / 128), 256, 0, stream>>>(A16, WT16, bias, tab, Qb, Kb);
  k_logits<<<dim3(SEQ / 128, SEQ / 128, BATCH * NHEADS), 256, 0, stream>>>(Qb, Kb, mask, out);
}

// Round 2
// 147.200 us; speedup vs baseline: 1.0462x; 1.0462x over previous
//
#include <hip/hip_runtime.h>
#include <hip/hip_bf16.h>
#include <stdint.h>

#define NHEADS 12
#define HSZ 64
#define BATCH 8
#define SEQ 1024
#define DIN 1024
#define NPROJ 1536   // NHEADS*HSZ*2
#define MTOK 8192    // BATCH*SEQ
#define NEGV 1e12f

typedef float  f32x4  __attribute__((ext_vector_type(4)));
typedef __bf16 bf16x8 __attribute__((ext_vector_type(8)));

__device__ __forceinline__ ushort f2bf(float x) {
  union { float f; uint32_t u; } v; v.f = x;
  uint32_t r = v.u + 0x7FFFu + ((v.u >> 16) & 1u);
  return (ushort)(r >> 16);
}

__device__ __forceinline__ void async16(const void* g, void* l) {
  __builtin_amdgcn_global_load_lds(
      (const __attribute__((address_space(1))) uint32_t*)g,
      (__attribute__((address_space(3))) uint32_t*)l,
      16, 0, 0);
}

// ---------------- merged prep kernel ----------------
// blocks [0,2048): f32->bf16 convert of inputs (grid-stride)
// blocks [2048,2432): W transpose+convert -> Wt[n][k]
// blocks [2432,2560): rope sin/cos table
__global__ __launch_bounds__(256) void k_prep(
    const float* __restrict__ inp, const float* __restrict__ W,
    ushort* __restrict__ A16, ushort* __restrict__ Wt, float* __restrict__ tab) {
  const int blk = blockIdx.x;
  const int tid = threadIdx.x;
  if (blk < 2048) {
    const float4* in4 = (const float4*)inp;
    ushort4* out4 = (ushort4*)A16;
    const int n4 = MTOK * DIN / 4;
    int i = blk * 256 + tid;
    for (; i < n4; i += 2048 * 256) {
      float4 v = in4[i];
      ushort4 o;
      o.x = f2bf(v.x); o.y = f2bf(v.y); o.z = f2bf(v.z); o.w = f2bf(v.w);
      out4[i] = o;
    }
  } else if (blk < 2432) {
    __shared__ float tile[64][65];
    const int bb = blk - 2048;           // 384 = 24 x 16
    const int n0 = (bb % 24) * 64;
    const int k0 = (bb / 24) * 64;
    const int c  = tid & 63;
    const int r0 = (tid >> 6) * 16;
    #pragma unroll
    for (int rr = 0; rr < 16; ++rr)
      tile[r0 + rr][c] = W[(size_t)(k0 + r0 + rr) * NPROJ + n0 + c];
    __syncthreads();
    #pragma unroll
    for (int rr = 0; rr < 16; ++rr)
      Wt[(size_t)(n0 + r0 + rr) * DIN + k0 + c] = f2bf(tile[c][r0 + rr]);
  } else {
    const int t = (blk - 2432) * 256 + tid;  // 32768 total
    const int s = t >> 5, i = t & 31;
    const float p   = powf(10000.0f, (float)i / 32.0f);
    const float ang = (float)s / p;
    tab[2 * t]     = sinf(ang);
    tab[2 * t + 1] = cosf(ang);
  }
}

// ---------------- projection GEMM + RoPE ----------------
// A: [MTOK][DIN] bf16, Bt: [NPROJ][DIN] bf16 (pre-transposed W)
// out: Qb/Kb [BATCH*NHEADS][SEQ][64] bf16 (RoPE'd)
// 1-D grid 768 blocks, XCD-swizzled: each XCD owns 8 contiguous m-tiles x all 12 n-tiles
__global__ __launch_bounds__(256) void k_gemm_proj(
    const ushort* __restrict__ A, const ushort* __restrict__ Bt,
    const float* __restrict__ bias, const float* __restrict__ tab,
    ushort* __restrict__ Qb, ushort* __restrict__ Kb) {
  __shared__ __align__(16) ushort As[128 * 32];
  __shared__ __align__(16) ushort Bs[128 * 32];
  const int tid  = threadIdx.x;
  const int lane = tid & 63;
  const int wid  = tid >> 6;
  const int wm = wid >> 1, wn = wid & 1;
  // XCD-aware remap (bijective: 768 % 8 == 0)
  const int orig = blockIdx.x;
  const int wgid = (orig & 7) * 96 + (orig >> 3);
  const int m0 = (wgid / 12) * 128;
  const int n0 = (wgid % 12) * 128;

  // staging: linear LDS layout [row][32] bf16 (64 B rows, 4 x 16B slots).
  // swizzle: slot_lds = slot_global ^ ((row>>1)&3)  (involution; applied to SOURCE)
  const int off0 = tid * 16;         // issue-0 linear byte offset in tile
  const int off1 = 4096 + tid * 16;  // issue-1
  const int r0 = off0 >> 6, s0 = (off0 >> 4) & 3;
  const int r1 = off1 >> 6, s1 = (off1 >> 4) & 3;
  const int g0 = (s0 ^ ((r0 >> 1) & 3)) * 8;  // global k-chunk (elements)
  const int g1 = (s1 ^ ((r1 >> 1) & 3)) * 8;
  const ushort* gA0 = A  + (size_t)(m0 + r0) * DIN + g0;
  const ushort* gA1 = A  + (size_t)(m0 + r1) * DIN + g1;
  const ushort* gB0 = Bt + (size_t)(n0 + r0) * DIN + g0;
  const ushort* gB1 = Bt + (size_t)(n0 + r1) * DIN + g1;
  ushort* lA0 = As + wid * 512;         // byte base wid*1024 (+lane*16 by HW)
  ushort* lA1 = As + 2048 + wid * 512;
  ushort* lB0 = Bs + wid * 512;
  ushort* lB1 = Bs + 2048 + wid * 512;

  // fragment read offsets (ushort units), same swizzle on READ side
  const int kb = lane >> 4;
  int aoff[4], boff[4];
  #pragma unroll
  for (int i = 0; i < 4; ++i) {
    const int ra = wm * 64 + i * 16 + (lane & 15);
    aoff[i] = ra * 32 + (kb ^ ((ra >> 1) & 3)) * 8;
    const int rb = wn * 64 + i * 16 + (lane & 15);
    boff[i] = rb * 32 + (kb ^ ((rb >> 1) & 3)) * 8;
  }

  f32x4 acc[4][4] = {};
  for (int kt = 0; kt < DIN / 32; ++kt) {
    __syncthreads();
    const int ko = kt * 32;
    async16(gA0 + ko, lA0);
    async16(gA1 + ko, lA1);
    async16(gB0 + ko, lB0);
    async16(gB1 + ko, lB1);
    __syncthreads();
    bf16x8 af[4], bfr[4];
    #pragma unroll
    for (int i = 0; i < 4; ++i) {
      af[i]  = *(const bf16x8*)(As + aoff[i]);
      bfr[i] = *(const bf16x8*)(Bs + boff[i]);
    }
    #pragma unroll
    for (int mi = 0; mi < 4; ++mi)
      #pragma unroll
      for (int ni = 0; ni < 4; ++ni)
        acc[mi][ni] = __builtin_amdgcn_mfma_f32_16x16x32_bf16(af[mi], bfr[ni], acc[mi][ni], 0, 0, 0);
  }

  // epilogue: bias + RoPE + scatter to Q/K (bf16)
  const int b = m0 >> 10;  // 128-tile never crosses a batch boundary
  const int baserow = m0 + wm * 64 + ((lane >> 4) << 2);
  #pragma unroll
  for (int ni = 0; ni < 4; ++ni) {
    const int n = n0 + wn * 64 + ni * 16 + (lane & 15);
    const float bv = bias[n];
    const int h  = n >> 7;
    const int c  = n & 127;
    const int d  = c & 63;
    const int pi = d >> 1;
    ushort* dst = ((c < 64) ? Qb : Kb) + (size_t)(b * NHEADS + h) * SEQ * 64 + d;
    #pragma unroll
    for (int mi = 0; mi < 4; ++mi) {
      #pragma unroll
      for (int j = 0; j < 4; ++j) {
        const int gm = baserow + mi * 16 + j;
        const int s  = gm & (SEQ - 1);
        float v = acc[mi][ni][j] + bv;
        float p = __shfl_xor(v, 1);  // paired channel (n^1) lives in lane^1
        float2 sc = ((const float2*)tab)[s * 32 + pi];
        float o = (d & 1) ? fmaf(v, sc.y, p * sc.x) : fmaf(v, sc.y, -p * sc.x);
        dst[(size_t)s * 64] = f2bf(o);
      }
    }
  }
}

// ---------------- logits: batched QK^T + mask ----------------
// 1-D grid 6144 blocks, XCD-swizzled: each XCD owns 12 contiguous bh slices
__global__ __launch_bounds__(256) void k_logits(
    const ushort* __restrict__ Qb, const ushort* __restrict__ Kb,
    const int* __restrict__ mask, float* __restrict__ out) {
  __shared__ __align__(16) ushort Qs[128 * 64];
  __shared__ __align__(16) ushort Ks[128 * 64];
  const int tid  = threadIdx.x;
  const int lane = tid & 63;
  const int wid  = tid >> 6;
  const int wm = wid >> 1, wn = wid & 1;
  // XCD-aware remap (bijective: 6144 % 8 == 0)
  const int orig = blockIdx.x;
  const int wgid = (orig & 7) * 768 + (orig >> 3);
  const int bh = wgid >> 6;              // 0..95
  const int b  = bh / NHEADS;
  const int m0 = ((wgid >> 3) & 7) * 128;
  const int n0 = (wgid & 7) * 128;
  const ushort* Qt = Qb + (size_t)bh * SEQ * 64;
  const ushort* Kt = Kb + (size_t)bh * SEQ * 64;

  // stage 128x64 bf16 tiles; rows are 128 B = 8 x 16B slots.
  // swizzle slot' = slot ^ (row&7) (else 32-way bank conflict on ds_read_b128)
  #pragma unroll
  for (int is = 0; is < 4; ++is) {
    const int off = is * 4096 + tid * 16;
    const int row = off >> 7;
    const int g8  = ((((off >> 4) & 7) ^ (row & 7))) * 8;
    async16(Qt + (size_t)(m0 + row) * 64 + g8, Qs + is * 2048 + wid * 512);
    async16(Kt + (size_t)(n0 + row) * 64 + g8, Ks + is * 2048 + wid * 512);
  }
  __syncthreads();

  f32x4 acc[4][4] = {};
  const int kb = lane >> 4;
  #pragma unroll
  for (int ks = 0; ks < 2; ++ks) {
    bf16x8 qf[4], kf[4];
    #pragma unroll
    for (int i = 0; i < 4; ++i) {
      const int rq = wm * 64 + i * 16 + (lane & 15);
      qf[i] = *(const bf16x8*)(Qs + rq * 64 + ((ks * 4 + kb) ^ (rq & 7)) * 8);
      const int rk = wn * 64 + i * 16 + (lane & 15);
      kf[i] = *(const bf16x8*)(Ks + rk * 64 + ((ks * 4 + kb) ^ (rk & 7)) * 8);
    }
    #pragma unroll
    for (int mi = 0; mi < 4; ++mi)
      #pragma unroll
      for (int ni = 0; ni < 4; ++ni)
        acc[mi][ni] = __builtin_amdgcn_mfma_f32_16x16x32_bf16(qf[mi], kf[ni], acc[mi][ni], 0, 0, 0);
  }

  const int* mb = mask + b * SEQ;
  float* ob = out + (size_t)bh * SEQ * SEQ;
  const int mrow0 = m0 + wm * 64 + ((lane >> 4) << 2);
  const int ncol0 = n0 + wn * 64 + (lane & 15);
  float npen[4];
  int gn_[4];
  #pragma unroll
  for (int ni = 0; ni < 4; ++ni) {
    gn_[ni]  = ncol0 + ni * 16;
    npen[ni] = mb[gn_[ni]] ? 0.0f : NEGV;
  }
  #pragma unroll
  for (int mi = 0; mi < 4; ++mi) {
    #pragma unroll
    for (int j = 0; j < 4; ++j) {
      const int gm = mrow0 + mi * 16 + j;
      const float mpen = mb[gm] ? 0.0f : NEGV;
      float* orow = ob + (size_t)gm * SEQ;
      #pragma unroll
      for (int ni = 0; ni < 4; ++ni) {
        const int gn = gn_[ni];
        const float tpen = (gm > gn) ? NEGV : 0.0f;
        orow[gn] = (acc[mi][ni][j] - (mpen + npen[ni] + tpen)) * 0.125f;
      }
    }
  }
}

// ---------------- launcher ----------------
extern "C" void kernel_launch(void* const* d_in, const int* in_sizes, int n_in,
                              void* d_out, int out_size, void* d_ws, size_t ws_size,
                              hipStream_t stream) {
  const float* inp  = (const float*)d_in[0];  // [8][1024][1024]
  const float* W    = (const float*)d_in[1];  // [1024][1536]
  const float* bias = (const float*)d_in[2];  // [1536]
  const int*   mask = (const int*)d_in[3];    // [8][1024]
  float* out = (float*)d_out;                 // [8][12][1024][1024]

  char* ws = (char*)d_ws;
  ushort* A16  = (ushort*)ws;                 // 16,777,216 B
  ushort* WT16 = (ushort*)(ws + 16777216);    //  3,145,728 B
  float*  tab  = (float*)(ws + 19922944);     //    262,144 B
  ushort* Qb   = (ushort*)(ws + 20185088);    // 12,582,912 B
  ushort* Kb   = (ushort*)(ws + 32768000);    // 12,582,912 B  (total ~45.4 MB)

  k_prep<<<2560, 256, 0, stream>>>(inp, W, A16, WT16, tab);
  k_gemm_proj<<<768, 256, 0, stream>>>(A16, WT16, bias, tab, Qb, Kb);
  k_logits<<<6144, 256, 0, stream>>>(Qb, Kb, mask, out);
}